// Round 1
// baseline (692.317 us; speedup 1.0000x reference)
//
#include <hip/hip_runtime.h>
#include <hip/hip_bf16.h>
#include <math.h>

// RWKV-7 Tmix forward, B=4 T=1024 C=1024 H=16 N=64.
// R11: recur_kernel rewritten: drop LDS ring + manual vmcnt; load packed step
// records DIRECTLY into registers per-lane (global_load_dwordx4), double-
// buffered 8 steps deep, __launch_bounds__(64,1) to unlock the VGPR budget
// (grid pins occupancy at 1 wave/SIMD anyway; 68-VGPR allocation was starving
// the scheduler of pipelining room -> 36% VALUBusy, ~340 stall cy/step).
// Input dtype (f32 vs bf16) runtime-detected.

using bf16 = __hip_bfloat16;
typedef __attribute__((ext_vector_type(8))) short bf16x8;
typedef __attribute__((ext_vector_type(4))) float f32x4;

#define DEVINL __device__ __forceinline__

DEVINL float b2f(bf16 v) { return __bfloat162float(v); }
DEVINL bf16 f2b(float f) { return __float2bfloat16(f); }
DEVINL float sigm(float x) { return 1.f / (1.f + __expf(-x)); }
DEVINL float bfbits2f(unsigned short s) { return __uint_as_float(((unsigned)s) << 16); }
DEVINL float lo16(unsigned u) { return __uint_as_float(u << 16); }
DEVINL float hi16(unsigned u) { return __uint_as_float(u & 0xffff0000u); }
DEVINL float ldin(const void* p, size_t i, int fl) {
  return fl ? ((const float*)p)[i] : b2f(((const bf16*)p)[i]);
}

DEVINL void g2lds16(const void* g, void* l) {
  __builtin_amdgcn_global_load_lds(
      (__attribute__((address_space(1))) void*)(g),
      (__attribute__((address_space(3))) void*)(l), 16, 0, 0);
}

template<int CTRL>
DEVINL float dpp_add(float x) {
  int t = __builtin_amdgcn_update_dpp(0, __float_as_int(x), CTRL, 0xf, 0xf, true);
  return x + __int_as_float(t);
}
DEVINL float rowsum16(float x) {
  x = dpp_add<0x121>(x);  // row_ror:1
  x = dpp_add<0x122>(x);  // row_ror:2
  x = dpp_add<0x124>(x);  // row_ror:4
  x = dpp_add<0x128>(x);  // row_ror:8
  return x;
}

// Packed stream addressing (shorts): step base = ((b*16+h)*1024 + t)*512
// [0,256): j*4 + slot (0=r 1=k 2=a 3=b)  [256,320): v[n]  floats [160,224): w[n]
DEVINL size_t stream_sb(int row, int h) {
  return ((size_t)((row >> 10) * 16 + h) * 1024 + (row & 1023)) * 512;
}

// ---------------- dtype probe: flag=1 -> inputs are f32 ----------------
__global__ void detect_kernel(const unsigned* __restrict__ x, int* __restrict__ flag) {
  __shared__ int cnt[4];
  int tid = threadIdx.x;
  unsigned w = x[tid];
  float v = fabsf(bfbits2f((unsigned short)(w & 0xffffu)));
  bool plaus = (v >= 1e-4f && v <= 16.f);
  unsigned long long m = __ballot(plaus);
  if ((tid & 63) == 0) cnt[tid >> 6] = __popcll(m);
  __syncthreads();
  if (tid == 0) *flag = (cnt[0] + cnt[1] + cnt[2] + cnt[3] < 128) ? 1 : 0;
}

// ---------------- prep: mix + big-weight cvt + 8 small transposes ----------------
__global__ __launch_bounds__(256)
void prep_kernel(const void* __restrict__ x,
    const void* mr, const void* mw, const void* mk,
    const void* mv, const void* ma, const void* mg,
    const void* W_r, const void* W_k, const void* W_v, const void* W_o,
    bf16* cWr, bf16* cWk, bf16* cWv, bf16* cWo,
    const void* w1, const void* w2, const void* a1, const void* a2,
    const void* v1, const void* v2, const void* g1, const void* g2,
    bf16* w1t, bf16* w2t, bf16* a1t, bf16* a2t,
    bf16* v1t, bf16* v2t, bf16* g1t, bf16* g2t,
    const int* __restrict__ flag,
    bf16* oxr, bf16* oxw, bf16* oxk, bf16* oxv, bf16* oxa, bf16* oxg)
{
  int fl = *flag;
  int bx = blockIdx.x;
  if (bx < 16384) {                       // token-shift mix over 4M
    size_t idx = (size_t)bx * 256 + threadIdx.x;
    int c = (int)(idx & 1023);
    int t = (int)((idx >> 10) & 1023);
    float xc = ldin(x, idx, fl);
    float px = (t == 0) ? 0.f : ldin(x, idx - 1024, fl);
    float dx = px - xc;
    oxr[idx] = f2b(xc + ldin(mr, c, fl) * dx);
    oxw[idx] = f2b(xc + ldin(mw, c, fl) * dx);
    oxk[idx] = f2b(xc + ldin(mk, c, fl) * dx);
    oxv[idx] = f2b(xc + ldin(mv, c, fl) * dx);
    oxa[idx] = f2b(xc + ldin(ma, c, fl) * dx);
    oxg[idx] = f2b(xc + ldin(mg, c, fl) * dx);
  } else if (bx < 32768) {                // big-weight convert, 4 x 1M
    int g = (bx - 16384) * 256 + threadIdx.x;
    int seg = g >> 20, i = g & 1048575;
    const void* s = seg == 0 ? W_r : seg == 1 ? W_k : seg == 2 ? W_v : W_o;
    bf16* d = seg == 0 ? cWr : seg == 1 ? cWk : seg == 2 ? cWv : cWo;
    d[i] = fl ? f2b(((const float*)s)[i]) : ((const bf16*)s)[i];
  } else {                                // 8 small transposes [K,N]->[N,K]
    int idx = (bx - 32768) * 256 + threadIdx.x;
    if (idx >= 655360) return;
    const int ends[8] = {65536, 131072, 196608, 262144, 294912, 327680, 491520, 655360};
    const int Ks[8] = {1024, 64, 1024, 64, 1024, 32, 1024, 160};
    const int Nd[8] = {64, 1024, 64, 1024, 32, 1024, 160, 1024};
    const void* srcs[8] = {w1, w2, a1, a2, v1, v2, g1, g2};
    bf16* dsts[8] = {w1t, w2t, a1t, a2t, v1t, v2t, g1t, g2t};
    int seg = 0, start = 0;
#pragma unroll
    for (int s2 = 0; s2 < 7; s2++)
      if (idx >= ends[s2]) { seg = s2 + 1; start = ends[s2]; }
    int local = idx - start;
    int K = Ks[seg], N = Nd[seg];
    int k = local / N, n = local - k * N;
    dsts[seg][(size_t)n * K + k] = f2b(ldin(srcs[seg], local, fl));
  }
}

// ---------------- shared MFMA GEMM core: C[M,N] = A[M,K] * B[N,K]^T ----------------
template<typename Epi>
DEVINL void gemm_core(const bf16* __restrict__ A, const bf16* __restrict__ Bt,
                      int K, int Brows, int m0, int n0, Epi&& epi)
{
  __shared__ short As[128 * 32];
  __shared__ short Bs[128 * 32];
  const int tid = threadIdx.x;
  const int wid = tid >> 6, lane = tid & 63;
  const int wr = (wid >> 1) * 64, wc = (wid & 1) * 64;

  f32x4 acc[4][4] = {};

  const int lrow = lane >> 2;
  const int lcol = (lane & 3) * 8;
  int arow0 = m0 + (wid * 2 + 0) * 16 + lrow;
  int arow1 = m0 + (wid * 2 + 1) * 16 + lrow;
  int brow0 = n0 + (wid * 2 + 0) * 16 + lrow; if (brow0 >= Brows) brow0 = Brows - 1;
  int brow1 = n0 + (wid * 2 + 1) * 16 + lrow; if (brow1 >= Brows) brow1 = Brows - 1;

  const short* Ag = (const short*)A;
  const short* Bg = (const short*)Bt;

  for (int kk = 0; kk < K; kk += 32) {
    __syncthreads();
    g2lds16(Ag + (size_t)arow0 * K + kk + lcol, As + (wid * 2 + 0) * 512);
    g2lds16(Ag + (size_t)arow1 * K + kk + lcol, As + (wid * 2 + 1) * 512);
    g2lds16(Bg + (size_t)brow0 * K + kk + lcol, Bs + (wid * 2 + 0) * 512);
    g2lds16(Bg + (size_t)brow1 * K + kk + lcol, Bs + (wid * 2 + 1) * 512);
    __syncthreads();
    bf16x8 af[4], bfr[4];
#pragma unroll
    for (int mi = 0; mi < 4; mi++)
      af[mi] = *(const bf16x8*)(As + (wr + mi * 16 + (lane & 15)) * 32 + (lane >> 4) * 8);
#pragma unroll
    for (int ni = 0; ni < 4; ni++)
      bfr[ni] = *(const bf16x8*)(Bs + (wc + ni * 16 + (lane & 15)) * 32 + (lane >> 4) * 8);
#pragma unroll
    for (int mi = 0; mi < 4; mi++)
#pragma unroll
      for (int ni = 0; ni < 4; ni++)
        acc[mi][ni] = __builtin_amdgcn_mfma_f32_16x16x32_bf16(af[mi], bfr[ni], acc[mi][ni], 0, 0, 0);
  }

  const int cl0 = lane & 15, r0 = (lane >> 4) * 4;
#pragma unroll
  for (int mi = 0; mi < 4; mi++)
#pragma unroll
    for (int ni = 0; ni < 4; ni++) {
      int col = n0 + wc + ni * 16 + cl0;
#pragma unroll
      for (int rr = 0; rr < 4; rr++)
        epi(m0 + wr + mi * 16 + r0 + rr, col, acc[mi][ni][rr]);
    }
}

// ---------------- stage1: xw@w1 tanh | xa@a1 | xv@v1 | xg@g1 sigm ----------------
__global__ __launch_bounds__(256)
void stage1_kernel(const bf16* xw, const bf16* xa, const bf16* xv, const bf16* xg,
                   const bf16* w1t, const bf16* a1t, const bf16* v1t, const bf16* g1t,
                   bf16* hw, bf16* ha, bf16* hv, bf16* hg)
{
  int y = blockIdx.y;
  int seg = (y <= 2) ? y : 3;
  int n0 = (y == 4) ? 128 : 0;
  const bf16* A  = seg == 0 ? xw  : seg == 1 ? xa  : seg == 2 ? xv  : xg;
  const bf16* Bt = seg == 0 ? w1t : seg == 1 ? a1t : seg == 2 ? v1t : g1t;
  int NS         = seg == 0 ? 64  : seg == 1 ? 64  : seg == 2 ? 32  : 160;
  bf16* out      = seg == 0 ? hw  : seg == 1 ? ha  : seg == 2 ? hv  : hg;
  gemm_core(A, Bt, 1024, NS, blockIdx.x * 128, n0, [&](int row, int col, float f) {
    if (col >= NS) return;
    if (seg == 0) f = tanhf(f);
    else if (seg == 3) f = sigm(f);
    out[(size_t)row * NS + col] = f2b(f);
  });
}

// ---------------- big r/k/v projections -> packed stream ----------------
__global__ __launch_bounds__(256)
void bigrkv_kernel(const bf16* xr, const bf16* xk, const bf16* xv,
                   const bf16* cWr, const bf16* cWk, const bf16* cWv,
                   bf16* __restrict__ STR)
{
  int z = blockIdx.z;
  const bf16* A  = z == 0 ? xr  : z == 1 ? xk  : xv;
  const bf16* Bt = z == 0 ? cWr : z == 1 ? cWk : cWv;
  gemm_core(A, Bt, 1024, 1024, blockIdx.x * 128, blockIdx.y * 128,
            [&](int row, int col, float f) {
    size_t sb = stream_sb(row, col >> 6);
    int n = col & 63;
    size_t off = (z == 2) ? (sb + 256 + n) : (sb + n * 4 + z);  // r->slot0 kraw->slot1 v->v
    STR[off] = f2b(f);
  });
}

// ---------------- stage2: wdec | asig->slot2 | vblend->v | G ----------------
__global__ __launch_bounds__(256)
void stage2_kernel(const bf16* hw, const bf16* ha, const bf16* hv, const bf16* hg,
                   const bf16* w2t, const bf16* a2t, const bf16* v2t, const bf16* g2t,
                   bf16* __restrict__ STR, float* __restrict__ STRf, float* __restrict__ G,
                   const void* w0, const void* a0, const void* v0p, const void* vfirst,
                   const int* __restrict__ flag)
{
  int fl = *flag;
  int z = blockIdx.z;
  const bf16* A  = z == 0 ? hw  : z == 1 ? ha  : z == 2 ? hv  : hg;
  const bf16* Bt = z == 0 ? w2t : z == 1 ? a2t : z == 2 ? v2t : g2t;
  int K          = z == 0 ? 64  : z == 1 ? 64  : z == 2 ? 32  : 160;
  gemm_core(A, Bt, K, 1024, blockIdx.x * 128, blockIdx.y * 128,
            [&](int row, int col, float f) {
    int n = col & 63;
    if (z == 0) {
      float zz = -(ldin(w0, col, fl) + f);
      float sp = fmaxf(zz, 0.f) + __logf(1.f + __expf(-fabsf(zz)));
      STRf[stream_sb(row, col >> 6) / 2 + 160 + n] = __expf(-__expf(-sp - 0.5f));
    } else if (z == 1) {
      STR[stream_sb(row, col >> 6) + n * 4 + 2] = f2b(sigm(ldin(a0, col, fl) + f));
    } else if (z == 2) {
      float sg = sigm(ldin(v0p, col, fl) + f);
      size_t pa = stream_sb(row, col >> 6) + 256 + n;
      float vr = b2f(STR[pa]);
      float vf = ldin(vfirst, (size_t)row * 1024 + col, fl);
      STR[pa] = f2b(vr + (vf - vr) * sg);
    } else {
      G[(size_t)row * 1024 + col] = f;
    }
  });
}

// ---------------- per-(t,h) finalize: kkn->slot2, b->slot3, kfinal->slot1 ----------------
__global__ __launch_bounds__(256)
void post_kernel(bf16* __restrict__ STR, const void* __restrict__ kkw,
                 const void* __restrict__ kaw, const int* __restrict__ flag) {
  int fl = *flag;
  int slot = blockIdx.x * 4 + (threadIdx.x >> 6);
  int tg = slot >> 4, h = slot & 15;
  int n = threadIdx.x & 63, c = h * 64 + n;
  size_t sb = stream_sb(tg, h);
  float kraw = b2f(STR[sb + n * 4 + 1]);
  float asig = b2f(STR[sb + n * 4 + 2]);
  float kk = kraw * ldin(kkw, c, fl);
  float ss = kk * kk;
  ss += __shfl_xor(ss, 1);  ss += __shfl_xor(ss, 2);  ss += __shfl_xor(ss, 4);
  ss += __shfl_xor(ss, 8);  ss += __shfl_xor(ss, 16); ss += __shfl_xor(ss, 32);
  float kkn = kk / fmaxf(sqrtf(ss), 1e-12f);
  STR[sb + n * 4 + 2] = f2b(kkn);
  STR[sb + n * 4 + 3] = f2b(-kkn * asig);
  STR[sb + n * 4 + 1] = f2b(kraw * (1.f + (asig - 1.f) * ldin(kaw, c, fl)));
}

// ---------------- sequential recurrence: register double-buffered pipeline ----------------
// 1024 single-wave blocks. blk = sib*64 + bh. Wave owns rows [sib*4,+4);
// lane: rl=lane>>4, jq=lane&15 (4 j's each). Per-lane DIRECT global loads of
// the step record slices (2x dwordx4 rkab, 1x dwordx4 w, 1x ushort v); 4-way
// same-address lanes dedup in the coalescer; 16x sibling replication is
// absorbed by L2/L3 (identical addresses to the old g2lds path). Two named
// register banks of CH=8 steps (all indices unroll-constant -> stays in VGPRs;
// __launch_bounds__(64,1) unlocks the budget). Compiler's in-order vmcnt
// tracking pipelines chunk t+1's 32 loads under chunk t's ~900cy of compute.
// Overreads <=2*CH steps past stream end (lands in pad/next stream) - benign.
#define CH 8
__global__ __launch_bounds__(64, 1)
void recur_kernel(const char* __restrict__ STR, float* __restrict__ Y) {
  int blk = blockIdx.x;
  int bh = blk & 63, sib = blk >> 6;
  int b = bh >> 4, h = bh & 15;
  int lane = threadIdx.x;
  int jq = lane & 15, rl = lane >> 4;
  int i = sib * 4 + rl;

  const char* rec = STR + (size_t)bh * (1024 * 1024);
  const char* prk = rec + jq * 32;          // rkab slice: 32B = 4 j's x 4 slots
  const char* pv  = rec + 512 + i * 2;      // v[i] bf16
  const char* pw  = rec + 640 + jq * 16;    // w float4
  float* yout = Y + (size_t)b * 1024 * 1024 + h * 64 + i;

  uint4 am0[CH], am1[CH]; float4 awv[CH]; unsigned short avu[CH];
  uint4 bm0[CH], bm1[CH]; float4 bwv[CH]; unsigned short bvu[CH];

  float S0 = 0.f, S1 = 0.f, S2 = 0.f, S3 = 0.f;

#define RLOAD(M0, M1, WV, VU, TT) do { \
    size_t _o = (size_t)(TT) * 1024; \
    M0 = *(const uint4*)(prk + _o); \
    M1 = *(const uint4*)(prk + _o + 16); \
    WV = *(const float4*)(pw + _o); \
    VU = *(const unsigned short*)(pv + _o); \
  } while (0)

#define RSTEP(M0, M1, WV, VU, TT) do { \
    float vi = bfbits2f(VU); \
    float rx = lo16(M0.x), kx = hi16(M0.x), ax = lo16(M0.y), bxx = hi16(M0.y); \
    float ry = lo16(M0.z), ky = hi16(M0.z), ay = lo16(M0.w), byy = hi16(M0.w); \
    float rz = lo16(M1.x), kz = hi16(M1.x), az = lo16(M1.y), bzz = hi16(M1.y); \
    float rw2 = lo16(M1.z), kw2 = hi16(M1.z), aw2 = lo16(M1.w), bww = hi16(M1.w); \
    float sa = (S0 * ax + S1 * ay) + (S2 * az + S3 * aw2); \
    sa = rowsum16(sa); \
    S0 = S0 * WV.x + (sa * bxx + vi * kx); \
    S1 = S1 * WV.y + (sa * byy + vi * ky); \
    S2 = S2 * WV.z + (sa * bzz + vi * kz); \
    S3 = S3 * WV.w + (sa * bww + vi * kw2); \
    float yy = (S0 * rx + S1 * ry) + (S2 * rz + S3 * rw2); \
    yy = rowsum16(yy); \
    if (jq == 0) yout[(size_t)(TT) * 1024] = yy; \
  } while (0)

#pragma unroll
  for (int d = 0; d < CH; ++d) RLOAD(am0[d], am1[d], awv[d], avu[d], d);

  for (int t0 = 0; t0 < 1024; t0 += 2 * CH) {
#pragma unroll
    for (int d = 0; d < CH; ++d) RLOAD(bm0[d], bm1[d], bwv[d], bvu[d], t0 + CH + d);
#pragma unroll
    for (int d = 0; d < CH; ++d) RSTEP(am0[d], am1[d], awv[d], avu[d], t0 + d);
#pragma unroll
    for (int d = 0; d < CH; ++d) RLOAD(am0[d], am1[d], awv[d], avu[d], t0 + 2 * CH + d);
#pragma unroll
    for (int d = 0; d < CH; ++d) RSTEP(bm0[d], bm1[d], bwv[d], bvu[d], t0 + CH + d);
  }
#undef RLOAD
#undef RSTEP
}

// ---------------- GroupNorm + residual + g gate ----------------
__global__ __launch_bounds__(256)
void gn_kernel(const float* __restrict__ Y, const bf16* __restrict__ STR,
               const float* __restrict__ G,
               const void* __restrict__ gw, const void* __restrict__ gb,
               const void* __restrict__ rk, const int* __restrict__ flag,
               bf16* __restrict__ Z)
{
  int fl = *flag;
  int slot = blockIdx.x * 4 + (threadIdx.x >> 6);
  int tg = slot >> 4, h = slot & 15;
  int n = threadIdx.x & 63, c = h * 64 + n;
  size_t sb = stream_sb(tg, h);
  float y = Y[(size_t)tg * 1024 + c];
  float rr = b2f(STR[sb + n * 4]), kf = b2f(STR[sb + n * 4 + 1]), vv = b2f(STR[sb + 256 + n]);
  float s1 = y, s2 = y * y, s3 = rr * kf * ldin(rk, c, fl);
#pragma unroll
  for (int m = 1; m < 64; m <<= 1) {
    s1 += __shfl_xor(s1, m);
    s2 += __shfl_xor(s2, m);
    s3 += __shfl_xor(s3, m);
  }
  float mu = s1 * 0.015625f;
  float var = s2 * 0.015625f - mu * mu;
  float xn = (y - mu) * rsqrtf(var + 0.00064f);
  float yn = xn * ldin(gw, c, fl) + ldin(gb, c, fl);
  yn += s3 * vv;
  Z[(size_t)tg * 1024 + c] = f2b(yn * G[(size_t)tg * 1024 + c]);
}

// ---------------- final output GEMM ----------------
__global__ __launch_bounds__(256)
void outgemm_kernel(const bf16* Z, const bf16* cWo,
                    float* oF, bf16* oB, const int* __restrict__ flag)
{
  int fl = *flag;
  gemm_core(Z, cWo, 1024, 1024, blockIdx.x * 128, blockIdx.y * 128,
            [&](int row, int col, float f) {
    if (fl) oF[(size_t)row * 1024 + col] = f;
    else    oB[(size_t)row * 1024 + col] = f2b(f);
  });
}

extern "C" void kernel_launch(void* const* d_in, const int* in_sizes, int n_in,
                              void* d_out, int out_size, void* d_ws, size_t ws_size,
                              hipStream_t stream)
{
  const void* x      = d_in[0];
  const void* vfirst = d_in[1];
  const void* m_r = d_in[2];  const void* m_w = d_in[3];
  const void* m_k = d_in[4];  const void* m_v = d_in[5];
  const void* m_a = d_in[6];  const void* m_g = d_in[7];
  const void* w0  = d_in[8];  const void* w1  = d_in[9];  const void* w2  = d_in[10];
  const void* a0  = d_in[11]; const void* a1  = d_in[12]; const void* a2  = d_in[13];
  const void* v0p = d_in[14]; const void* v1  = d_in[15]; const void* v2  = d_in[16];
  const void* g1  = d_in[17]; const void* g2  = d_in[18];
  const void* k_k = d_in[19]; const void* k_a = d_in[20]; const void* r_k = d_in[21];
  const void* W_r = d_in[22]; const void* W_k = d_in[23];
  const void* W_v = d_in[24]; const void* W_o = d_in[25];
  const void* gnw = d_in[26]; const void* gnb = d_in[27];
  (void)in_sizes; (void)n_in; (void)out_size; (void)ws_size;

  char* ws = (char*)d_ws;
  size_t off = 0;
  auto alloc = [&](size_t bytes) -> void* {
    void* p = ws + off; off += (bytes + 255) & ~(size_t)255; return p;
  };
  const size_t BTC2 = (size_t)4096 * 1024 * 2;
  int*  flag = (int*)alloc(256);
  bf16* cWr = (bf16*)alloc((size_t)1048576 * 2);
  bf16* cWk = (bf16*)alloc((size_t)1048576 * 2);
  bf16* cWv = (bf16*)alloc((size_t)1048576 * 2);
  bf16* cWo = (bf16*)alloc((size_t)1048576 * 2);
  bf16* w1t = (bf16*)alloc((size_t)65536 * 2);
  bf16* w2t = (bf16*)alloc((size_t)65536 * 2);
  bf16* a1t = (bf16*)alloc((size_t)65536 * 2);
  bf16* a2t = (bf16*)alloc((size_t)65536 * 2);
  bf16* v1t = (bf16*)alloc((size_t)32768 * 2);
  bf16* v2t = (bf16*)alloc((size_t)32768 * 2);
  bf16* g1t = (bf16*)alloc((size_t)163840 * 2);
  bf16* g2t = (bf16*)alloc((size_t)163840 * 2);
  bf16* xr = (bf16*)alloc(BTC2);
  bf16* xw = (bf16*)alloc(BTC2);
  bf16* xk = (bf16*)alloc(BTC2);
  bf16* xv = (bf16*)alloc(BTC2);
  bf16* xa = (bf16*)alloc(BTC2);
  bf16* xg = (bf16*)alloc(BTC2);
  char* STR = (char*)alloc((size_t)64 * 1024 * 1024 + 16384);  // packed [B*H][T][1024B] + overread pad
  bf16* hw  = (bf16*)alloc((size_t)4096 * 64 * 2);
  bf16* ha  = (bf16*)alloc((size_t)4096 * 64 * 2);
  bf16* hv  = (bf16*)alloc((size_t)4096 * 32 * 2);
  bf16* hg  = (bf16*)alloc((size_t)4096 * 160 * 2);
  // dead-buffer reuse (lifetimes verified by launch order):
  float* G = (float*)xr;   // over xr+xw; written by stage2 (after stage1/bigrkv consume)
  float* Y = (float*)xk;   // over xk+xv; written by recur
  bf16*  Z = xa;           // written by gn (after stage1 consumes xa)

  detect_kernel<<<1, 256, 0, stream>>>((const unsigned*)x, flag);
  prep_kernel<<<35328, 256, 0, stream>>>(
      x, m_r, m_w, m_k, m_v, m_a, m_g,
      W_r, W_k, W_v, W_o, cWr, cWk, cWv, cWo,
      w1, w2, a1, a2, v1, v2, g1, g2,
      w1t, w2t, a1t, a2t, v1t, v2t, g1t, g2t,
      flag, xr, xw, xk, xv, xa, xg);

  stage1_kernel<<<dim3(32, 5), 256, 0, stream>>>(xw, xa, xv, xg,
                                                 w1t, a1t, v1t, g1t, hw, ha, hv, hg);
  bigrkv_kernel<<<dim3(32, 8, 3), 256, 0, stream>>>(xr, xk, xv, cWr, cWk, cWv, (bf16*)STR);
  stage2_kernel<<<dim3(32, 8, 4), 256, 0, stream>>>(hw, ha, hv, hg,
                                                    w2t, a2t, v2t, g2t,
                                                    (bf16*)STR, (float*)STR, G,
                                                    w0, a0, v0p, vfirst, flag);
  post_kernel<<<16384, 256, 0, stream>>>((bf16*)STR, k_k, k_a, flag);
  recur_kernel<<<1024, 64, 0, stream>>>(STR, Y);
  gn_kernel<<<16384, 256, 0, stream>>>(Y, (bf16*)STR, G, gnw, gnb, r_k, flag, Z);
  outgemm_kernel<<<dim3(32, 8), 256, 0, stream>>>(Z, cWo, (float*)d_out, (bf16*)d_out, flag);
}

// Round 2
// 571.314 us; speedup vs baseline: 1.2118x; 1.2118x over previous
//
#include <hip/hip_runtime.h>
#include <hip/hip_bf16.h>
#include <math.h>

// RWKV-7 Tmix forward, B=4 T=1024 C=1024 H=16 N=64.
// R12: revert R11's direct-reg loads (compiler sank+spilled: VGPR=116, +8MB
// scratch writes). Back to R10's LDS ring (g2lds + vmcnt(8) gate), plus:
//  (a) 1-step-ahead register prefetch of the LDS record slices (26 extra
//      VGPRs, 2 banks) so step d's ~110cy VALU hides step d+1's ~120cy
//      ds_read latency (R10 exposed it every step -> 36% VALUBusy).
//  (b) conflict-free rkab layout: each quad's 32B split into two 16B
//      half-regions (A=[0,256)B, B=[256,512)B, quad q at q*16) -> lane
//      stride 16B -> 2-way bank alias (free) instead of 4-way (8.4M
//      conflict-cycles). m0/m1 register contents unchanged.
// Input dtype (f32 vs bf16) runtime-detected.

using bf16 = __hip_bfloat16;
typedef __attribute__((ext_vector_type(8))) short bf16x8;
typedef __attribute__((ext_vector_type(4))) float f32x4;

#define DEVINL __device__ __forceinline__

DEVINL float b2f(bf16 v) { return __bfloat162float(v); }
DEVINL bf16 f2b(float f) { return __float2bfloat16(f); }
DEVINL float sigm(float x) { return 1.f / (1.f + __expf(-x)); }
DEVINL float bfbits2f(unsigned short s) { return __uint_as_float(((unsigned)s) << 16); }
DEVINL float lo16(unsigned u) { return __uint_as_float(u << 16); }
DEVINL float hi16(unsigned u) { return __uint_as_float(u & 0xffff0000u); }
DEVINL float ldin(const void* p, size_t i, int fl) {
  return fl ? ((const float*)p)[i] : b2f(((const bf16*)p)[i]);
}

DEVINL void g2lds16(const void* g, void* l) {
  __builtin_amdgcn_global_load_lds(
      (__attribute__((address_space(1))) void*)(g),
      (__attribute__((address_space(3))) void*)(l), 16, 0, 0);
}

// wait until at most 8 vmem ops outstanding (drains all older ops);
// memory-clobber fences pin ds_read ordering around it.
DEVINL void wait_vmcnt8() {
  __asm__ volatile("" ::: "memory");
  __builtin_amdgcn_s_waitcnt(0x0F78);   // lgkmcnt=15 expcnt=7 vmcnt=8
  __asm__ volatile("" ::: "memory");
}

template<int CTRL>
DEVINL float dpp_add(float x) {
  int t = __builtin_amdgcn_update_dpp(0, __float_as_int(x), CTRL, 0xf, 0xf, true);
  return x + __int_as_float(t);
}
DEVINL float rowsum16(float x) {
  x = dpp_add<0x121>(x);  // row_ror:1
  x = dpp_add<0x122>(x);  // row_ror:2
  x = dpp_add<0x124>(x);  // row_ror:4
  x = dpp_add<0x128>(x);  // row_ror:8
  return x;
}

// Packed stream addressing (shorts): step base = ((b*16+h)*1024 + t)*512
// rkab region (split halves): u=n*4+slot -> short index
//   ((u>>3)&1)*128 + (u>>4)*8 + (u&7)   (A=[0,128) shorts, B=[128,256))
// [256,320): v[n] bf16   floats [160,224): w[n]
DEVINL size_t stream_sb(int row, int h) {
  return ((size_t)((row >> 10) * 16 + h) * 1024 + (row & 1023)) * 512;
}
DEVINL size_t slotoff(int n, int s) {
  int u = n * 4 + s;
  return (size_t)(((u >> 3) & 1) * 128 + ((u >> 4) << 3) + (u & 7));
}

// ---------------- dtype probe: flag=1 -> inputs are f32 ----------------
__global__ void detect_kernel(const unsigned* __restrict__ x, int* __restrict__ flag) {
  __shared__ int cnt[4];
  int tid = threadIdx.x;
  unsigned w = x[tid];
  float v = fabsf(bfbits2f((unsigned short)(w & 0xffffu)));
  bool plaus = (v >= 1e-4f && v <= 16.f);
  unsigned long long m = __ballot(plaus);
  if ((tid & 63) == 0) cnt[tid >> 6] = __popcll(m);
  __syncthreads();
  if (tid == 0) *flag = (cnt[0] + cnt[1] + cnt[2] + cnt[3] < 128) ? 1 : 0;
}

// ---------------- prep: mix + big-weight cvt + 8 small transposes ----------------
__global__ __launch_bounds__(256)
void prep_kernel(const void* __restrict__ x,
    const void* mr, const void* mw, const void* mk,
    const void* mv, const void* ma, const void* mg,
    const void* W_r, const void* W_k, const void* W_v, const void* W_o,
    bf16* cWr, bf16* cWk, bf16* cWv, bf16* cWo,
    const void* w1, const void* w2, const void* a1, const void* a2,
    const void* v1, const void* v2, const void* g1, const void* g2,
    bf16* w1t, bf16* w2t, bf16* a1t, bf16* a2t,
    bf16* v1t, bf16* v2t, bf16* g1t, bf16* g2t,
    const int* __restrict__ flag,
    bf16* oxr, bf16* oxw, bf16* oxk, bf16* oxv, bf16* oxa, bf16* oxg)
{
  int fl = *flag;
  int bx = blockIdx.x;
  if (bx < 16384) {                       // token-shift mix over 4M
    size_t idx = (size_t)bx * 256 + threadIdx.x;
    int c = (int)(idx & 1023);
    int t = (int)((idx >> 10) & 1023);
    float xc = ldin(x, idx, fl);
    float px = (t == 0) ? 0.f : ldin(x, idx - 1024, fl);
    float dx = px - xc;
    oxr[idx] = f2b(xc + ldin(mr, c, fl) * dx);
    oxw[idx] = f2b(xc + ldin(mw, c, fl) * dx);
    oxk[idx] = f2b(xc + ldin(mk, c, fl) * dx);
    oxv[idx] = f2b(xc + ldin(mv, c, fl) * dx);
    oxa[idx] = f2b(xc + ldin(ma, c, fl) * dx);
    oxg[idx] = f2b(xc + ldin(mg, c, fl) * dx);
  } else if (bx < 32768) {                // big-weight convert, 4 x 1M
    int g = (bx - 16384) * 256 + threadIdx.x;
    int seg = g >> 20, i = g & 1048575;
    const void* s = seg == 0 ? W_r : seg == 1 ? W_k : seg == 2 ? W_v : W_o;
    bf16* d = seg == 0 ? cWr : seg == 1 ? cWk : seg == 2 ? cWv : cWo;
    d[i] = fl ? f2b(((const float*)s)[i]) : ((const bf16*)s)[i];
  } else {                                // 8 small transposes [K,N]->[N,K]
    int idx = (bx - 32768) * 256 + threadIdx.x;
    if (idx >= 655360) return;
    const int ends[8] = {65536, 131072, 196608, 262144, 294912, 327680, 491520, 655360};
    const int Ks[8] = {1024, 64, 1024, 64, 1024, 32, 1024, 160};
    const int Nd[8] = {64, 1024, 64, 1024, 32, 1024, 160, 1024};
    const void* srcs[8] = {w1, w2, a1, a2, v1, v2, g1, g2};
    bf16* dsts[8] = {w1t, w2t, a1t, a2t, v1t, v2t, g1t, g2t};
    int seg = 0, start = 0;
#pragma unroll
    for (int s2 = 0; s2 < 7; s2++)
      if (idx >= ends[s2]) { seg = s2 + 1; start = ends[s2]; }
    int local = idx - start;
    int K = Ks[seg], N = Nd[seg];
    int k = local / N, n = local - k * N;
    dsts[seg][(size_t)n * K + k] = f2b(ldin(srcs[seg], local, fl));
  }
}

// ---------------- shared MFMA GEMM core: C[M,N] = A[M,K] * B[N,K]^T ----------------
template<typename Epi>
DEVINL void gemm_core(const bf16* __restrict__ A, const bf16* __restrict__ Bt,
                      int K, int Brows, int m0, int n0, Epi&& epi)
{
  __shared__ short As[128 * 32];
  __shared__ short Bs[128 * 32];
  const int tid = threadIdx.x;
  const int wid = tid >> 6, lane = tid & 63;
  const int wr = (wid >> 1) * 64, wc = (wid & 1) * 64;

  f32x4 acc[4][4] = {};

  const int lrow = lane >> 2;
  const int lcol = (lane & 3) * 8;
  int arow0 = m0 + (wid * 2 + 0) * 16 + lrow;
  int arow1 = m0 + (wid * 2 + 1) * 16 + lrow;
  int brow0 = n0 + (wid * 2 + 0) * 16 + lrow; if (brow0 >= Brows) brow0 = Brows - 1;
  int brow1 = n0 + (wid * 2 + 1) * 16 + lrow; if (brow1 >= Brows) brow1 = Brows - 1;

  const short* Ag = (const short*)A;
  const short* Bg = (const short*)Bt;

  for (int kk = 0; kk < K; kk += 32) {
    __syncthreads();
    g2lds16(Ag + (size_t)arow0 * K + kk + lcol, As + (wid * 2 + 0) * 512);
    g2lds16(Ag + (size_t)arow1 * K + kk + lcol, As + (wid * 2 + 1) * 512);
    g2lds16(Bg + (size_t)brow0 * K + kk + lcol, Bs + (wid * 2 + 0) * 512);
    g2lds16(Bg + (size_t)brow1 * K + kk + lcol, Bs + (wid * 2 + 1) * 512);
    __syncthreads();
    bf16x8 af[4], bfr[4];
#pragma unroll
    for (int mi = 0; mi < 4; mi++)
      af[mi] = *(const bf16x8*)(As + (wr + mi * 16 + (lane & 15)) * 32 + (lane >> 4) * 8);
#pragma unroll
    for (int ni = 0; ni < 4; ni++)
      bfr[ni] = *(const bf16x8*)(Bs + (wc + ni * 16 + (lane & 15)) * 32 + (lane >> 4) * 8);
#pragma unroll
    for (int mi = 0; mi < 4; mi++)
#pragma unroll
      for (int ni = 0; ni < 4; ni++)
        acc[mi][ni] = __builtin_amdgcn_mfma_f32_16x16x32_bf16(af[mi], bfr[ni], acc[mi][ni], 0, 0, 0);
  }

  const int cl0 = lane & 15, r0 = (lane >> 4) * 4;
#pragma unroll
  for (int mi = 0; mi < 4; mi++)
#pragma unroll
    for (int ni = 0; ni < 4; ni++) {
      int col = n0 + wc + ni * 16 + cl0;
#pragma unroll
      for (int rr = 0; rr < 4; rr++)
        epi(m0 + wr + mi * 16 + r0 + rr, col, acc[mi][ni][rr]);
    }
}

// ---------------- stage1: xw@w1 tanh | xa@a1 | xv@v1 | xg@g1 sigm ----------------
__global__ __launch_bounds__(256)
void stage1_kernel(const bf16* xw, const bf16* xa, const bf16* xv, const bf16* xg,
                   const bf16* w1t, const bf16* a1t, const bf16* v1t, const bf16* g1t,
                   bf16* hw, bf16* ha, bf16* hv, bf16* hg)
{
  int y = blockIdx.y;
  int seg = (y <= 2) ? y : 3;
  int n0 = (y == 4) ? 128 : 0;
  const bf16* A  = seg == 0 ? xw  : seg == 1 ? xa  : seg == 2 ? xv  : xg;
  const bf16* Bt = seg == 0 ? w1t : seg == 1 ? a1t : seg == 2 ? v1t : g1t;
  int NS         = seg == 0 ? 64  : seg == 1 ? 64  : seg == 2 ? 32  : 160;
  bf16* out      = seg == 0 ? hw  : seg == 1 ? ha  : seg == 2 ? hv  : hg;
  gemm_core(A, Bt, 1024, NS, blockIdx.x * 128, n0, [&](int row, int col, float f) {
    if (col >= NS) return;
    if (seg == 0) f = tanhf(f);
    else if (seg == 3) f = sigm(f);
    out[(size_t)row * NS + col] = f2b(f);
  });
}

// ---------------- big r/k/v projections -> packed stream ----------------
__global__ __launch_bounds__(256)
void bigrkv_kernel(const bf16* xr, const bf16* xk, const bf16* xv,
                   const bf16* cWr, const bf16* cWk, const bf16* cWv,
                   bf16* __restrict__ STR)
{
  int z = blockIdx.z;
  const bf16* A  = z == 0 ? xr  : z == 1 ? xk  : xv;
  const bf16* Bt = z == 0 ? cWr : z == 1 ? cWk : cWv;
  gemm_core(A, Bt, 1024, 1024, blockIdx.x * 128, blockIdx.y * 128,
            [&](int row, int col, float f) {
    size_t sb = stream_sb(row, col >> 6);
    int n = col & 63;
    size_t off = (z == 2) ? (sb + 256 + n) : (sb + slotoff(n, z));  // r->s0 kraw->s1 v->v
    STR[off] = f2b(f);
  });
}

// ---------------- stage2: wdec | asig->slot2 | vblend->v | G ----------------
__global__ __launch_bounds__(256)
void stage2_kernel(const bf16* hw, const bf16* ha, const bf16* hv, const bf16* hg,
                   const bf16* w2t, const bf16* a2t, const bf16* v2t, const bf16* g2t,
                   bf16* __restrict__ STR, float* __restrict__ STRf, float* __restrict__ G,
                   const void* w0, const void* a0, const void* v0p, const void* vfirst,
                   const int* __restrict__ flag)
{
  int fl = *flag;
  int z = blockIdx.z;
  const bf16* A  = z == 0 ? hw  : z == 1 ? ha  : z == 2 ? hv  : hg;
  const bf16* Bt = z == 0 ? w2t : z == 1 ? a2t : z == 2 ? v2t : g2t;
  int K          = z == 0 ? 64  : z == 1 ? 64  : z == 2 ? 32  : 160;
  gemm_core(A, Bt, K, 1024, blockIdx.x * 128, blockIdx.y * 128,
            [&](int row, int col, float f) {
    int n = col & 63;
    if (z == 0) {
      float zz = -(ldin(w0, col, fl) + f);
      float sp = fmaxf(zz, 0.f) + __logf(1.f + __expf(-fabsf(zz)));
      STRf[stream_sb(row, col >> 6) / 2 + 160 + n] = __expf(-__expf(-sp - 0.5f));
    } else if (z == 1) {
      STR[stream_sb(row, col >> 6) + slotoff(n, 2)] = f2b(sigm(ldin(a0, col, fl) + f));
    } else if (z == 2) {
      float sg = sigm(ldin(v0p, col, fl) + f);
      size_t pa = stream_sb(row, col >> 6) + 256 + n;
      float vr = b2f(STR[pa]);
      float vf = ldin(vfirst, (size_t)row * 1024 + col, fl);
      STR[pa] = f2b(vr + (vf - vr) * sg);
    } else {
      G[(size_t)row * 1024 + col] = f;
    }
  });
}

// ---------------- per-(t,h) finalize: kkn->slot2, b->slot3, kfinal->slot1 ----------------
__global__ __launch_bounds__(256)
void post_kernel(bf16* __restrict__ STR, const void* __restrict__ kkw,
                 const void* __restrict__ kaw, const int* __restrict__ flag) {
  int fl = *flag;
  int slot = blockIdx.x * 4 + (threadIdx.x >> 6);
  int tg = slot >> 4, h = slot & 15;
  int n = threadIdx.x & 63, c = h * 64 + n;
  size_t sb = stream_sb(tg, h);
  float kraw = b2f(STR[sb + slotoff(n, 1)]);
  float asig = b2f(STR[sb + slotoff(n, 2)]);
  float kk = kraw * ldin(kkw, c, fl);
  float ss = kk * kk;
  ss += __shfl_xor(ss, 1);  ss += __shfl_xor(ss, 2);  ss += __shfl_xor(ss, 4);
  ss += __shfl_xor(ss, 8);  ss += __shfl_xor(ss, 16); ss += __shfl_xor(ss, 32);
  float kkn = kk / fmaxf(sqrtf(ss), 1e-12f);
  STR[sb + slotoff(n, 2)] = f2b(kkn);
  STR[sb + slotoff(n, 3)] = f2b(-kkn * asig);
  STR[sb + slotoff(n, 1)] = f2b(kraw * (1.f + (asig - 1.f) * ldin(kaw, c, fl)));
}

// ---------------- sequential recurrence: LDS ring + reg-prefetch pipeline ----------------
// 1024 single-wave blocks. blk = sib*64 + bh (16 sibs per bh, same XCD).
// Wave owns rows [sib*4,+4); lane: rl=lane>>4, jq=lane&15 (4 j's each).
// g2lds (width16, 64 lanes) stages one 1024B step record; ring = 2 x 8 steps
// (16KB). vmcnt(8) after prefetch-issue guarantees current buffer retired.
// Within a chunk, step d+1's LDS slices are read into a 2-bank register
// rotation BEFORE step d's math -> ds_read latency hidden under ~110cy VALU.
// rkab half-region layout (slotoff) makes the b128 reads 2-way-bank (free).
// Overreads <=8 steps past stream end (lands in pad) - benign.
#define CH 8
__global__ __launch_bounds__(64, 1)
void recur_kernel(const char* __restrict__ STR, float* __restrict__ Y) {
  __shared__ __align__(16) char lds[2 * CH * 1024];
  int blk = blockIdx.x;
  int bh = blk & 63, sib = blk >> 6;
  int b = bh >> 4, h = bh & 15;
  int lane = threadIdx.x;
  int jq = lane & 15, rl = lane >> 4;
  int i = sib * 4 + rl;

  const char* gb = STR + (size_t)bh * (1024 * 1024) + lane * 16;
  float* yout = Y + (size_t)b * 1024 * 1024 + h * 64 + i;

  const char* pa = lds + jq * 16;         // rkab half A (n%4 in {0,1})
  const char* pb = lds + 256 + jq * 16;   // rkab half B (n%4 in {2,3})
  const char* pv = lds + 512 + i * 2;     // v base
  const char* pw = lds + 640 + jq * 16;   // w base

#pragma unroll
  for (int d = 0; d < CH; ++d)
    g2lds16(gb + (size_t)d * 1024, lds + d * 1024);

  float S0 = 0.f, S1 = 0.f, S2 = 0.f, S3 = 0.f;
  uint4 m0r[2], m1r[2]; float4 wvr[2]; unsigned short vur[2];

#define RLOAD(BK, SO) do { \
    m0r[BK] = *(const uint4*)(pa + (SO)); \
    m1r[BK] = *(const uint4*)(pb + (SO)); \
    wvr[BK] = *(const float4*)(pw + (SO)); \
    vur[BK] = *(const unsigned short*)(pv + (SO)); \
  } while (0)

#define RSTEP(BK, TT) do { \
    uint4 M0 = m0r[BK], M1 = m1r[BK]; float4 WV = wvr[BK]; \
    float vi = bfbits2f(vur[BK]); \
    float rx = lo16(M0.x), kx = hi16(M0.x), ax = lo16(M0.y), bxx = hi16(M0.y); \
    float ry = lo16(M0.z), ky = hi16(M0.z), ay = lo16(M0.w), byy = hi16(M0.w); \
    float rz = lo16(M1.x), kz = hi16(M1.x), az = lo16(M1.y), bzz = hi16(M1.y); \
    float rw2 = lo16(M1.z), kw2 = hi16(M1.z), aw2 = lo16(M1.w), bww = hi16(M1.w); \
    float sa = (S0 * ax + S1 * ay) + (S2 * az + S3 * aw2); \
    sa = rowsum16(sa); \
    S0 = S0 * WV.x + (sa * bxx + vi * kx); \
    S1 = S1 * WV.y + (sa * byy + vi * ky); \
    S2 = S2 * WV.z + (sa * bzz + vi * kz); \
    S3 = S3 * WV.w + (sa * bww + vi * kw2); \
    float yy = (S0 * rx + S1 * ry) + (S2 * rz + S3 * rw2); \
    yy = rowsum16(yy); \
    if (jq == 0) yout[(size_t)(TT) * 1024] = yy; \
  } while (0)

  for (int t0 = 0; t0 < 1024; t0 += CH) {
    int cur = (t0 >> 3) & 1;
    int cbase = cur * (CH * 1024);
    char* bufn = lds + (cur ^ 1) * (CH * 1024);
    // issue next CH step records into the other buffer (fire-and-forget)
#pragma unroll
    for (int d = 0; d < CH; ++d)
      g2lds16(gb + (size_t)(t0 + CH + d) * 1024, bufn + d * 1024);
    // drain everything older than the 8 just-issued loads -> current buf ready
    wait_vmcnt8();
    // software-pipelined compute: prefetch step d+1 regs before step d math
    RLOAD(0, cbase);
#pragma unroll
    for (int d = 0; d < CH; ++d) {
      if (d + 1 < CH) RLOAD((d + 1) & 1, cbase + (d + 1) * 1024);
      RSTEP(d & 1, t0 + d);
    }
  }
#undef RLOAD
#undef RSTEP
}

// ---------------- GroupNorm + residual + g gate ----------------
__global__ __launch_bounds__(256)
void gn_kernel(const float* __restrict__ Y, const bf16* __restrict__ STR,
               const float* __restrict__ G,
               const void* __restrict__ gw, const void* __restrict__ gb,
               const void* __restrict__ rk, const int* __restrict__ flag,
               bf16* __restrict__ Z)
{
  int fl = *flag;
  int slot = blockIdx.x * 4 + (threadIdx.x >> 6);
  int tg = slot >> 4, h = slot & 15;
  int n = threadIdx.x & 63, c = h * 64 + n;
  size_t sb = stream_sb(tg, h);
  float y = Y[(size_t)tg * 1024 + c];
  float rr = b2f(STR[sb + slotoff(n, 0)]);
  float kf = b2f(STR[sb + slotoff(n, 1)]);
  float vv = b2f(STR[sb + 256 + n]);
  float s1 = y, s2 = y * y, s3 = rr * kf * ldin(rk, c, fl);
#pragma unroll
  for (int m = 1; m < 64; m <<= 1) {
    s1 += __shfl_xor(s1, m);
    s2 += __shfl_xor(s2, m);
    s3 += __shfl_xor(s3, m);
  }
  float mu = s1 * 0.015625f;
  float var = s2 * 0.015625f - mu * mu;
  float xn = (y - mu) * rsqrtf(var + 0.00064f);
  float yn = xn * ldin(gw, c, fl) + ldin(gb, c, fl);
  yn += s3 * vv;
  Z[(size_t)tg * 1024 + c] = f2b(yn * G[(size_t)tg * 1024 + c]);
}

// ---------------- final output GEMM ----------------
__global__ __launch_bounds__(256)
void outgemm_kernel(const bf16* Z, const bf16* cWo,
                    float* oF, bf16* oB, const int* __restrict__ flag)
{
  int fl = *flag;
  gemm_core(Z, cWo, 1024, 1024, blockIdx.x * 128, blockIdx.y * 128,
            [&](int row, int col, float f) {
    if (fl) oF[(size_t)row * 1024 + col] = f;
    else    oB[(size_t)row * 1024 + col] = f2b(f);
  });
}

extern "C" void kernel_launch(void* const* d_in, const int* in_sizes, int n_in,
                              void* d_out, int out_size, void* d_ws, size_t ws_size,
                              hipStream_t stream)
{
  const void* x      = d_in[0];
  const void* vfirst = d_in[1];
  const void* m_r = d_in[2];  const void* m_w = d_in[3];
  const void* m_k = d_in[4];  const void* m_v = d_in[5];
  const void* m_a = d_in[6];  const void* m_g = d_in[7];
  const void* w0  = d_in[8];  const void* w1  = d_in[9];  const void* w2  = d_in[10];
  const void* a0  = d_in[11]; const void* a1  = d_in[12]; const void* a2  = d_in[13];
  const void* v0p = d_in[14]; const void* v1  = d_in[15]; const void* v2  = d_in[16];
  const void* g1  = d_in[17]; const void* g2  = d_in[18];
  const void* k_k = d_in[19]; const void* k_a = d_in[20]; const void* r_k = d_in[21];
  const void* W_r = d_in[22]; const void* W_k = d_in[23];
  const void* W_v = d_in[24]; const void* W_o = d_in[25];
  const void* gnw = d_in[26]; const void* gnb = d_in[27];
  (void)in_sizes; (void)n_in; (void)out_size; (void)ws_size;

  char* ws = (char*)d_ws;
  size_t off = 0;
  auto alloc = [&](size_t bytes) -> void* {
    void* p = ws + off; off += (bytes + 255) & ~(size_t)255; return p;
  };
  const size_t BTC2 = (size_t)4096 * 1024 * 2;
  int*  flag = (int*)alloc(256);
  bf16* cWr = (bf16*)alloc((size_t)1048576 * 2);
  bf16* cWk = (bf16*)alloc((size_t)1048576 * 2);
  bf16* cWv = (bf16*)alloc((size_t)1048576 * 2);
  bf16* cWo = (bf16*)alloc((size_t)1048576 * 2);
  bf16* w1t = (bf16*)alloc((size_t)65536 * 2);
  bf16* w2t = (bf16*)alloc((size_t)65536 * 2);
  bf16* a1t = (bf16*)alloc((size_t)65536 * 2);
  bf16* a2t = (bf16*)alloc((size_t)65536 * 2);
  bf16* v1t = (bf16*)alloc((size_t)32768 * 2);
  bf16* v2t = (bf16*)alloc((size_t)32768 * 2);
  bf16* g1t = (bf16*)alloc((size_t)163840 * 2);
  bf16* g2t = (bf16*)alloc((size_t)163840 * 2);
  bf16* xr = (bf16*)alloc(BTC2);
  bf16* xw = (bf16*)alloc(BTC2);
  bf16* xk = (bf16*)alloc(BTC2);
  bf16* xv = (bf16*)alloc(BTC2);
  bf16* xa = (bf16*)alloc(BTC2);
  bf16* xg = (bf16*)alloc(BTC2);
  char* STR = (char*)alloc((size_t)64 * 1024 * 1024 + 16384);  // packed [B*H][T][1024B] + overread pad
  bf16* hw  = (bf16*)alloc((size_t)4096 * 64 * 2);
  bf16* ha  = (bf16*)alloc((size_t)4096 * 64 * 2);
  bf16* hv  = (bf16*)alloc((size_t)4096 * 32 * 2);
  bf16* hg  = (bf16*)alloc((size_t)4096 * 160 * 2);
  // dead-buffer reuse (lifetimes verified by launch order):
  float* G = (float*)xr;   // over xr+xw; written by stage2 (after stage1/bigrkv consume)
  float* Y = (float*)xk;   // over xk+xv; written by recur
  bf16*  Z = xa;           // written by gn (after stage1 consumes xa)

  detect_kernel<<<1, 256, 0, stream>>>((const unsigned*)x, flag);
  prep_kernel<<<35328, 256, 0, stream>>>(
      x, m_r, m_w, m_k, m_v, m_a, m_g,
      W_r, W_k, W_v, W_o, cWr, cWk, cWv, cWo,
      w1, w2, a1, a2, v1, v2, g1, g2,
      w1t, w2t, a1t, a2t, v1t, v2t, g1t, g2t,
      flag, xr, xw, xk, xv, xa, xg);

  stage1_kernel<<<dim3(32, 5), 256, 0, stream>>>(xw, xa, xv, xg,
                                                 w1t, a1t, v1t, g1t, hw, ha, hv, hg);
  bigrkv_kernel<<<dim3(32, 8, 3), 256, 0, stream>>>(xr, xk, xv, cWr, cWk, cWv, (bf16*)STR);
  stage2_kernel<<<dim3(32, 8, 4), 256, 0, stream>>>(hw, ha, hv, hg,
                                                    w2t, a2t, v2t, g2t,
                                                    (bf16*)STR, (float*)STR, G,
                                                    w0, a0, v0p, vfirst, flag);
  post_kernel<<<16384, 256, 0, stream>>>((bf16*)STR, k_k, k_a, flag);
  recur_kernel<<<1024, 64, 0, stream>>>(STR, Y);
  gn_kernel<<<16384, 256, 0, stream>>>(Y, (bf16*)STR, G, gnw, gnb, r_k, flag, Z);
  outgemm_kernel<<<dim3(32, 8), 256, 0, stream>>>(Z, cWo, (float*)d_out, (bf16*)d_out, flag);
}

// Round 3
// 568.720 us; speedup vs baseline: 1.2173x; 1.0046x over previous
//
#include <hip/hip_runtime.h>
#include <hip/hip_bf16.h>
#include <math.h>

// RWKV-7 Tmix forward, B=4 T=1024 C=1024 H=16 N=64.
// R13: R12 + FORCED 1-step-ahead LDS->reg pipeline in recur_kernel.
// R12's C++-level prefetch was undone by the scheduler (VGPR stayed 68,
// VALUBusy stayed 37%). Now: ds_reads are inline-asm (opaque, pinned),
// per step d we issue d+1's 4 reads, s_waitcnt lgkmcnt(4) (drain d's reads
// only), sched_barrier(0) (rule #18), then compute d. ds_read latency
// (~150cy) hides under step compute (~200-250cy). g2lds ring + vmcnt(8)
// gate unchanged. rkab half-region layout (2-way bank, free) unchanged.
// Input dtype (f32 vs bf16) runtime-detected.

using bf16 = __hip_bfloat16;
typedef __attribute__((ext_vector_type(8))) short bf16x8;
typedef __attribute__((ext_vector_type(4))) float f32x4;

#define DEVINL __device__ __forceinline__

DEVINL float b2f(bf16 v) { return __bfloat162float(v); }
DEVINL bf16 f2b(float f) { return __float2bfloat16(f); }
DEVINL float sigm(float x) { return 1.f / (1.f + __expf(-x)); }
DEVINL float bfbits2f(unsigned short s) { return __uint_as_float(((unsigned)s) << 16); }
DEVINL float lo16(unsigned u) { return __uint_as_float(u << 16); }
DEVINL float hi16(unsigned u) { return __uint_as_float(u & 0xffff0000u); }
DEVINL float ldin(const void* p, size_t i, int fl) {
  return fl ? ((const float*)p)[i] : b2f(((const bf16*)p)[i]);
}

DEVINL void g2lds16(const void* g, void* l) {
  __builtin_amdgcn_global_load_lds(
      (__attribute__((address_space(1))) void*)(g),
      (__attribute__((address_space(3))) void*)(l), 16, 0, 0);
}

// wait until at most 8 vmem ops outstanding (drains all older ops);
// memory-clobber fences pin ds_read ordering around it.
DEVINL void wait_vmcnt8() {
  __asm__ volatile("" ::: "memory");
  __builtin_amdgcn_s_waitcnt(0x0F78);   // lgkmcnt=15 expcnt=7 vmcnt=8
  __asm__ volatile("" ::: "memory");
}

template<int CTRL>
DEVINL float dpp_add(float x) {
  int t = __builtin_amdgcn_update_dpp(0, __float_as_int(x), CTRL, 0xf, 0xf, true);
  return x + __int_as_float(t);
}
DEVINL float rowsum16(float x) {
  x = dpp_add<0x121>(x);  // row_ror:1
  x = dpp_add<0x122>(x);  // row_ror:2
  x = dpp_add<0x124>(x);  // row_ror:4
  x = dpp_add<0x128>(x);  // row_ror:8
  return x;
}

// Packed stream addressing (shorts): step base = ((b*16+h)*1024 + t)*512
// rkab region (split halves): u=n*4+slot -> short index
//   ((u>>3)&1)*128 + (u>>4)*8 + (u&7)   (A=[0,128) shorts, B=[128,256))
// [256,320): v[n] bf16   floats [160,224): w[n]
DEVINL size_t stream_sb(int row, int h) {
  return ((size_t)((row >> 10) * 16 + h) * 1024 + (row & 1023)) * 512;
}
DEVINL size_t slotoff(int n, int s) {
  int u = n * 4 + s;
  return (size_t)(((u >> 3) & 1) * 128 + ((u >> 4) << 3) + (u & 7));
}

// ---------------- dtype probe: flag=1 -> inputs are f32 ----------------
__global__ void detect_kernel(const unsigned* __restrict__ x, int* __restrict__ flag) {
  __shared__ int cnt[4];
  int tid = threadIdx.x;
  unsigned w = x[tid];
  float v = fabsf(bfbits2f((unsigned short)(w & 0xffffu)));
  bool plaus = (v >= 1e-4f && v <= 16.f);
  unsigned long long m = __ballot(plaus);
  if ((tid & 63) == 0) cnt[tid >> 6] = __popcll(m);
  __syncthreads();
  if (tid == 0) *flag = (cnt[0] + cnt[1] + cnt[2] + cnt[3] < 128) ? 1 : 0;
}

// ---------------- prep: mix + big-weight cvt + 8 small transposes ----------------
__global__ __launch_bounds__(256)
void prep_kernel(const void* __restrict__ x,
    const void* mr, const void* mw, const void* mk,
    const void* mv, const void* ma, const void* mg,
    const void* W_r, const void* W_k, const void* W_v, const void* W_o,
    bf16* cWr, bf16* cWk, bf16* cWv, bf16* cWo,
    const void* w1, const void* w2, const void* a1, const void* a2,
    const void* v1, const void* v2, const void* g1, const void* g2,
    bf16* w1t, bf16* w2t, bf16* a1t, bf16* a2t,
    bf16* v1t, bf16* v2t, bf16* g1t, bf16* g2t,
    const int* __restrict__ flag,
    bf16* oxr, bf16* oxw, bf16* oxk, bf16* oxv, bf16* oxa, bf16* oxg)
{
  int fl = *flag;
  int bx = blockIdx.x;
  if (bx < 16384) {                       // token-shift mix over 4M
    size_t idx = (size_t)bx * 256 + threadIdx.x;
    int c = (int)(idx & 1023);
    int t = (int)((idx >> 10) & 1023);
    float xc = ldin(x, idx, fl);
    float px = (t == 0) ? 0.f : ldin(x, idx - 1024, fl);
    float dx = px - xc;
    oxr[idx] = f2b(xc + ldin(mr, c, fl) * dx);
    oxw[idx] = f2b(xc + ldin(mw, c, fl) * dx);
    oxk[idx] = f2b(xc + ldin(mk, c, fl) * dx);
    oxv[idx] = f2b(xc + ldin(mv, c, fl) * dx);
    oxa[idx] = f2b(xc + ldin(ma, c, fl) * dx);
    oxg[idx] = f2b(xc + ldin(mg, c, fl) * dx);
  } else if (bx < 32768) {                // big-weight convert, 4 x 1M
    int g = (bx - 16384) * 256 + threadIdx.x;
    int seg = g >> 20, i = g & 1048575;
    const void* s = seg == 0 ? W_r : seg == 1 ? W_k : seg == 2 ? W_v : W_o;
    bf16* d = seg == 0 ? cWr : seg == 1 ? cWk : seg == 2 ? cWv : cWo;
    d[i] = fl ? f2b(((const float*)s)[i]) : ((const bf16*)s)[i];
  } else {                                // 8 small transposes [K,N]->[N,K]
    int idx = (bx - 32768) * 256 + threadIdx.x;
    if (idx >= 655360) return;
    const int ends[8] = {65536, 131072, 196608, 262144, 294912, 327680, 491520, 655360};
    const int Ks[8] = {1024, 64, 1024, 64, 1024, 32, 1024, 160};
    const int Nd[8] = {64, 1024, 64, 1024, 32, 1024, 160, 1024};
    const void* srcs[8] = {w1, w2, a1, a2, v1, v2, g1, g2};
    bf16* dsts[8] = {w1t, w2t, a1t, a2t, v1t, v2t, g1t, g2t};
    int seg = 0, start = 0;
#pragma unroll
    for (int s2 = 0; s2 < 7; s2++)
      if (idx >= ends[s2]) { seg = s2 + 1; start = ends[s2]; }
    int local = idx - start;
    int K = Ks[seg], N = Nd[seg];
    int k = local / N, n = local - k * N;
    dsts[seg][(size_t)n * K + k] = f2b(ldin(srcs[seg], local, fl));
  }
}

// ---------------- shared MFMA GEMM core: C[M,N] = A[M,K] * B[N,K]^T ----------------
template<typename Epi>
DEVINL void gemm_core(const bf16* __restrict__ A, const bf16* __restrict__ Bt,
                      int K, int Brows, int m0, int n0, Epi&& epi)
{
  __shared__ short As[128 * 32];
  __shared__ short Bs[128 * 32];
  const int tid = threadIdx.x;
  const int wid = tid >> 6, lane = tid & 63;
  const int wr = (wid >> 1) * 64, wc = (wid & 1) * 64;

  f32x4 acc[4][4] = {};

  const int lrow = lane >> 2;
  const int lcol = (lane & 3) * 8;
  int arow0 = m0 + (wid * 2 + 0) * 16 + lrow;
  int arow1 = m0 + (wid * 2 + 1) * 16 + lrow;
  int brow0 = n0 + (wid * 2 + 0) * 16 + lrow; if (brow0 >= Brows) brow0 = Brows - 1;
  int brow1 = n0 + (wid * 2 + 1) * 16 + lrow; if (brow1 >= Brows) brow1 = Brows - 1;

  const short* Ag = (const short*)A;
  const short* Bg = (const short*)Bt;

  for (int kk = 0; kk < K; kk += 32) {
    __syncthreads();
    g2lds16(Ag + (size_t)arow0 * K + kk + lcol, As + (wid * 2 + 0) * 512);
    g2lds16(Ag + (size_t)arow1 * K + kk + lcol, As + (wid * 2 + 1) * 512);
    g2lds16(Bg + (size_t)brow0 * K + kk + lcol, Bs + (wid * 2 + 0) * 512);
    g2lds16(Bg + (size_t)brow1 * K + kk + lcol, Bs + (wid * 2 + 1) * 512);
    __syncthreads();
    bf16x8 af[4], bfr[4];
#pragma unroll
    for (int mi = 0; mi < 4; mi++)
      af[mi] = *(const bf16x8*)(As + (wr + mi * 16 + (lane & 15)) * 32 + (lane >> 4) * 8);
#pragma unroll
    for (int ni = 0; ni < 4; ni++)
      bfr[ni] = *(const bf16x8*)(Bs + (wc + ni * 16 + (lane & 15)) * 32 + (lane >> 4) * 8);
#pragma unroll
    for (int mi = 0; mi < 4; mi++)
#pragma unroll
      for (int ni = 0; ni < 4; ni++)
        acc[mi][ni] = __builtin_amdgcn_mfma_f32_16x16x32_bf16(af[mi], bfr[ni], acc[mi][ni], 0, 0, 0);
  }

  const int cl0 = lane & 15, r0 = (lane >> 4) * 4;
#pragma unroll
  for (int mi = 0; mi < 4; mi++)
#pragma unroll
    for (int ni = 0; ni < 4; ni++) {
      int col = n0 + wc + ni * 16 + cl0;
#pragma unroll
      for (int rr = 0; rr < 4; rr++)
        epi(m0 + wr + mi * 16 + r0 + rr, col, acc[mi][ni][rr]);
    }
}

// ---------------- stage1: xw@w1 tanh | xa@a1 | xv@v1 | xg@g1 sigm ----------------
__global__ __launch_bounds__(256)
void stage1_kernel(const bf16* xw, const bf16* xa, const bf16* xv, const bf16* xg,
                   const bf16* w1t, const bf16* a1t, const bf16* v1t, const bf16* g1t,
                   bf16* hw, bf16* ha, bf16* hv, bf16* hg)
{
  int y = blockIdx.y;
  int seg = (y <= 2) ? y : 3;
  int n0 = (y == 4) ? 128 : 0;
  const bf16* A  = seg == 0 ? xw  : seg == 1 ? xa  : seg == 2 ? xv  : xg;
  const bf16* Bt = seg == 0 ? w1t : seg == 1 ? a1t : seg == 2 ? v1t : g1t;
  int NS         = seg == 0 ? 64  : seg == 1 ? 64  : seg == 2 ? 32  : 160;
  bf16* out      = seg == 0 ? hw  : seg == 1 ? ha  : seg == 2 ? hv  : hg;
  gemm_core(A, Bt, 1024, NS, blockIdx.x * 128, n0, [&](int row, int col, float f) {
    if (col >= NS) return;
    if (seg == 0) f = tanhf(f);
    else if (seg == 3) f = sigm(f);
    out[(size_t)row * NS + col] = f2b(f);
  });
}

// ---------------- big r/k/v projections -> packed stream ----------------
__global__ __launch_bounds__(256)
void bigrkv_kernel(const bf16* xr, const bf16* xk, const bf16* xv,
                   const bf16* cWr, const bf16* cWk, const bf16* cWv,
                   bf16* __restrict__ STR)
{
  int z = blockIdx.z;
  const bf16* A  = z == 0 ? xr  : z == 1 ? xk  : xv;
  const bf16* Bt = z == 0 ? cWr : z == 1 ? cWk : cWv;
  gemm_core(A, Bt, 1024, 1024, blockIdx.x * 128, blockIdx.y * 128,
            [&](int row, int col, float f) {
    size_t sb = stream_sb(row, col >> 6);
    int n = col & 63;
    size_t off = (z == 2) ? (sb + 256 + n) : (sb + slotoff(n, z));  // r->s0 kraw->s1 v->v
    STR[off] = f2b(f);
  });
}

// ---------------- stage2: wdec | asig->slot2 | vblend->v | G ----------------
__global__ __launch_bounds__(256)
void stage2_kernel(const bf16* hw, const bf16* ha, const bf16* hv, const bf16* hg,
                   const bf16* w2t, const bf16* a2t, const bf16* v2t, const bf16* g2t,
                   bf16* __restrict__ STR, float* __restrict__ STRf, float* __restrict__ G,
                   const void* w0, const void* a0, const void* v0p, const void* vfirst,
                   const int* __restrict__ flag)
{
  int fl = *flag;
  int z = blockIdx.z;
  const bf16* A  = z == 0 ? hw  : z == 1 ? ha  : z == 2 ? hv  : hg;
  const bf16* Bt = z == 0 ? w2t : z == 1 ? a2t : z == 2 ? v2t : g2t;
  int K          = z == 0 ? 64  : z == 1 ? 64  : z == 2 ? 32  : 160;
  gemm_core(A, Bt, K, 1024, blockIdx.x * 128, blockIdx.y * 128,
            [&](int row, int col, float f) {
    int n = col & 63;
    if (z == 0) {
      float zz = -(ldin(w0, col, fl) + f);
      float sp = fmaxf(zz, 0.f) + __logf(1.f + __expf(-fabsf(zz)));
      STRf[stream_sb(row, col >> 6) / 2 + 160 + n] = __expf(-__expf(-sp - 0.5f));
    } else if (z == 1) {
      STR[stream_sb(row, col >> 6) + slotoff(n, 2)] = f2b(sigm(ldin(a0, col, fl) + f));
    } else if (z == 2) {
      float sg = sigm(ldin(v0p, col, fl) + f);
      size_t pa = stream_sb(row, col >> 6) + 256 + n;
      float vr = b2f(STR[pa]);
      float vf = ldin(vfirst, (size_t)row * 1024 + col, fl);
      STR[pa] = f2b(vr + (vf - vr) * sg);
    } else {
      G[(size_t)row * 1024 + col] = f;
    }
  });
}

// ---------------- per-(t,h) finalize: kkn->slot2, b->slot3, kfinal->slot1 ----------------
__global__ __launch_bounds__(256)
void post_kernel(bf16* __restrict__ STR, const void* __restrict__ kkw,
                 const void* __restrict__ kaw, const int* __restrict__ flag) {
  int fl = *flag;
  int slot = blockIdx.x * 4 + (threadIdx.x >> 6);
  int tg = slot >> 4, h = slot & 15;
  int n = threadIdx.x & 63, c = h * 64 + n;
  size_t sb = stream_sb(tg, h);
  float kraw = b2f(STR[sb + slotoff(n, 1)]);
  float asig = b2f(STR[sb + slotoff(n, 2)]);
  float kk = kraw * ldin(kkw, c, fl);
  float ss = kk * kk;
  ss += __shfl_xor(ss, 1);  ss += __shfl_xor(ss, 2);  ss += __shfl_xor(ss, 4);
  ss += __shfl_xor(ss, 8);  ss += __shfl_xor(ss, 16); ss += __shfl_xor(ss, 32);
  float kkn = kk / fmaxf(sqrtf(ss), 1e-12f);
  STR[sb + slotoff(n, 2)] = f2b(kkn);
  STR[sb + slotoff(n, 3)] = f2b(-kkn * asig);
  STR[sb + slotoff(n, 1)] = f2b(kraw * (1.f + (asig - 1.f) * ldin(kaw, c, fl)));
}

// ---------------- sequential recurrence: LDS ring + FORCED reg pipeline ----------------
// 1024 single-wave blocks. blk = sib*64 + bh (16 sibs per bh, same XCD).
// Wave owns rows [sib*4,+4); lane: rl=lane>>4, jq=lane&15 (4 j's each).
// g2lds (width16, 64 lanes) stages one 1024B step record; ring = 2 x 8 steps
// (16KB). vmcnt(8) after prefetch-issue guarantees current buffer retired.
// ds_reads are INLINE ASM (pinned); per step d: issue d+1's 4 reads ->
// s_waitcnt lgkmcnt(4) (drain d's only) -> sched_barrier(0) -> compute d.
// rkab half-region layout (slotoff) keeps b128 reads 2-way-bank (free).
// Overreads <=8 steps past stream end (lands in pad) - benign.
#define CH 8
__global__ __launch_bounds__(64, 1)
void recur_kernel(const char* __restrict__ STR, float* __restrict__ Y) {
  __shared__ __align__(16) char lds[2 * CH * 1024];
  int blk = blockIdx.x;
  int bh = blk & 63, sib = blk >> 6;
  int b = bh >> 4, h = bh & 15;
  int lane = threadIdx.x;
  int jq = lane & 15, rl = lane >> 4;
  int i = sib * 4 + rl;

  const char* gb = STR + (size_t)bh * (1024 * 1024) + lane * 16;
  float* yout = Y + (size_t)b * 1024 * 1024 + h * 64 + i;

  // 32-bit LDS byte offsets for the asm ds_reads
  unsigned lbase = (unsigned)(size_t)(__attribute__((address_space(3))) void*)(void*)lds;
  unsigned lA = lbase + (unsigned)(jq * 16);          // rkab half A
  unsigned lB = lbase + 256u + (unsigned)(jq * 16);   // rkab half B
  unsigned lV = lbase + 512u + (unsigned)(i * 2);     // v (bf16)
  unsigned lW = lbase + 640u + (unsigned)(jq * 16);   // w (float4)

#pragma unroll
  for (int d = 0; d < CH; ++d)
    g2lds16(gb + (size_t)d * 1024, lds + d * 1024);

  float S0 = 0.f, S1 = 0.f, S2 = 0.f, S3 = 0.f;
  uint4 m0r[2], m1r[2]; float4 wvr[2]; unsigned vur[2];

#define RLOAD(BK, SO) do { \
    unsigned _so = (unsigned)(SO); \
    asm volatile("ds_read_b128 %0, %1" : "=v"(m0r[BK]) : "v"(lA + _so)); \
    asm volatile("ds_read_b128 %0, %1" : "=v"(m1r[BK]) : "v"(lB + _so)); \
    asm volatile("ds_read_b128 %0, %1" : "=v"(wvr[BK]) : "v"(lW + _so)); \
    asm volatile("ds_read_u16  %0, %1" : "=v"(vur[BK]) : "v"(lV + _so)); \
  } while (0)

#define WAITL(N) do { \
    asm volatile("s_waitcnt lgkmcnt(" #N ")" ::: "memory"); \
    __builtin_amdgcn_sched_barrier(0); \
  } while (0)

#define RSTEP(BK, TT) do { \
    uint4 M0 = m0r[BK], M1 = m1r[BK]; float4 WV = wvr[BK]; \
    float vi = lo16(vur[BK]); \
    float rx = lo16(M0.x), kx = hi16(M0.x), ax = lo16(M0.y), bxx = hi16(M0.y); \
    float ry = lo16(M0.z), ky = hi16(M0.z), ay = lo16(M0.w), byy = hi16(M0.w); \
    float rz = lo16(M1.x), kz = hi16(M1.x), az = lo16(M1.y), bzz = hi16(M1.y); \
    float rw2 = lo16(M1.z), kw2 = hi16(M1.z), aw2 = lo16(M1.w), bww = hi16(M1.w); \
    float sa = (S0 * ax + S1 * ay) + (S2 * az + S3 * aw2); \
    sa = rowsum16(sa); \
    S0 = S0 * WV.x + (sa * bxx + vi * kx); \
    S1 = S1 * WV.y + (sa * byy + vi * ky); \
    S2 = S2 * WV.z + (sa * bzz + vi * kz); \
    S3 = S3 * WV.w + (sa * bww + vi * kw2); \
    float yy = (S0 * rx + S1 * ry) + (S2 * rz + S3 * rw2); \
    yy = rowsum16(yy); \
    if (jq == 0) yout[(size_t)(TT) * 1024] = yy; \
  } while (0)

  for (int t0 = 0; t0 < 1024; t0 += CH) {
    int cur = (t0 >> 3) & 1;
    unsigned cbase = (unsigned)(cur * (CH * 1024));
    char* bufn = lds + (cur ^ 1) * (CH * 1024);
    // issue next CH step records into the other buffer (fire-and-forget)
#pragma unroll
    for (int d = 0; d < CH; ++d)
      g2lds16(gb + (size_t)(t0 + CH + d) * 1024, bufn + d * 1024);
    // drain everything older than the 8 just-issued loads -> current buf ready
    wait_vmcnt8();
    // forced software pipeline: d+1's reads in flight during d's compute
    RLOAD(0, cbase);
#pragma unroll
    for (int d = 0; d < CH; ++d) {
      if (d + 1 < CH) { RLOAD((d + 1) & 1, cbase + (d + 1) * 1024); WAITL(4); }
      else            { WAITL(0); }
      RSTEP(d & 1, t0 + d);
    }
  }
#undef RLOAD
#undef WAITL
#undef RSTEP
}

// ---------------- GroupNorm + residual + g gate ----------------
__global__ __launch_bounds__(256)
void gn_kernel(const float* __restrict__ Y, const bf16* __restrict__ STR,
               const float* __restrict__ G,
               const void* __restrict__ gw, const void* __restrict__ gb,
               const void* __restrict__ rk, const int* __restrict__ flag,
               bf16* __restrict__ Z)
{
  int fl = *flag;
  int slot = blockIdx.x * 4 + (threadIdx.x >> 6);
  int tg = slot >> 4, h = slot & 15;
  int n = threadIdx.x & 63, c = h * 64 + n;
  size_t sb = stream_sb(tg, h);
  float y = Y[(size_t)tg * 1024 + c];
  float rr = b2f(STR[sb + slotoff(n, 0)]);
  float kf = b2f(STR[sb + slotoff(n, 1)]);
  float vv = b2f(STR[sb + 256 + n]);
  float s1 = y, s2 = y * y, s3 = rr * kf * ldin(rk, c, fl);
#pragma unroll
  for (int m = 1; m < 64; m <<= 1) {
    s1 += __shfl_xor(s1, m);
    s2 += __shfl_xor(s2, m);
    s3 += __shfl_xor(s3, m);
  }
  float mu = s1 * 0.015625f;
  float var = s2 * 0.015625f - mu * mu;
  float xn = (y - mu) * rsqrtf(var + 0.00064f);
  float yn = xn * ldin(gw, c, fl) + ldin(gb, c, fl);
  yn += s3 * vv;
  Z[(size_t)tg * 1024 + c] = f2b(yn * G[(size_t)tg * 1024 + c]);
}

// ---------------- final output GEMM ----------------
__global__ __launch_bounds__(256)
void outgemm_kernel(const bf16* Z, const bf16* cWo,
                    float* oF, bf16* oB, const int* __restrict__ flag)
{
  int fl = *flag;
  gemm_core(Z, cWo, 1024, 1024, blockIdx.x * 128, blockIdx.y * 128,
            [&](int row, int col, float f) {
    if (fl) oF[(size_t)row * 1024 + col] = f;
    else    oB[(size_t)row * 1024 + col] = f2b(f);
  });
}

extern "C" void kernel_launch(void* const* d_in, const int* in_sizes, int n_in,
                              void* d_out, int out_size, void* d_ws, size_t ws_size,
                              hipStream_t stream)
{
  const void* x      = d_in[0];
  const void* vfirst = d_in[1];
  const void* m_r = d_in[2];  const void* m_w = d_in[3];
  const void* m_k = d_in[4];  const void* m_v = d_in[5];
  const void* m_a = d_in[6];  const void* m_g = d_in[7];
  const void* w0  = d_in[8];  const void* w1  = d_in[9];  const void* w2  = d_in[10];
  const void* a0  = d_in[11]; const void* a1  = d_in[12]; const void* a2  = d_in[13];
  const void* v0p = d_in[14]; const void* v1  = d_in[15]; const void* v2  = d_in[16];
  const void* g1  = d_in[17]; const void* g2  = d_in[18];
  const void* k_k = d_in[19]; const void* k_a = d_in[20]; const void* r_k = d_in[21];
  const void* W_r = d_in[22]; const void* W_k = d_in[23];
  const void* W_v = d_in[24]; const void* W_o = d_in[25];
  const void* gnw = d_in[26]; const void* gnb = d_in[27];
  (void)in_sizes; (void)n_in; (void)out_size; (void)ws_size;

  char* ws = (char*)d_ws;
  size_t off = 0;
  auto alloc = [&](size_t bytes) -> void* {
    void* p = ws + off; off += (bytes + 255) & ~(size_t)255; return p;
  };
  const size_t BTC2 = (size_t)4096 * 1024 * 2;
  int*  flag = (int*)alloc(256);
  bf16* cWr = (bf16*)alloc((size_t)1048576 * 2);
  bf16* cWk = (bf16*)alloc((size_t)1048576 * 2);
  bf16* cWv = (bf16*)alloc((size_t)1048576 * 2);
  bf16* cWo = (bf16*)alloc((size_t)1048576 * 2);
  bf16* w1t = (bf16*)alloc((size_t)65536 * 2);
  bf16* w2t = (bf16*)alloc((size_t)65536 * 2);
  bf16* a1t = (bf16*)alloc((size_t)65536 * 2);
  bf16* a2t = (bf16*)alloc((size_t)65536 * 2);
  bf16* v1t = (bf16*)alloc((size_t)32768 * 2);
  bf16* v2t = (bf16*)alloc((size_t)32768 * 2);
  bf16* g1t = (bf16*)alloc((size_t)163840 * 2);
  bf16* g2t = (bf16*)alloc((size_t)163840 * 2);
  bf16* xr = (bf16*)alloc(BTC2);
  bf16* xw = (bf16*)alloc(BTC2);
  bf16* xk = (bf16*)alloc(BTC2);
  bf16* xv = (bf16*)alloc(BTC2);
  bf16* xa = (bf16*)alloc(BTC2);
  bf16* xg = (bf16*)alloc(BTC2);
  char* STR = (char*)alloc((size_t)64 * 1024 * 1024 + 16384);  // packed [B*H][T][1024B] + overread pad
  bf16* hw  = (bf16*)alloc((size_t)4096 * 64 * 2);
  bf16* ha  = (bf16*)alloc((size_t)4096 * 64 * 2);
  bf16* hv  = (bf16*)alloc((size_t)4096 * 32 * 2);
  bf16* hg  = (bf16*)alloc((size_t)4096 * 160 * 2);
  // dead-buffer reuse (lifetimes verified by launch order):
  float* G = (float*)xr;   // over xr+xw; written by stage2 (after stage1/bigrkv consume)
  float* Y = (float*)xk;   // over xk+xv; written by recur
  bf16*  Z = xa;           // written by gn (after stage1 consumes xa)

  detect_kernel<<<1, 256, 0, stream>>>((const unsigned*)x, flag);
  prep_kernel<<<35328, 256, 0, stream>>>(
      x, m_r, m_w, m_k, m_v, m_a, m_g,
      W_r, W_k, W_v, W_o, cWr, cWk, cWv, cWo,
      w1, w2, a1, a2, v1, v2, g1, g2,
      w1t, w2t, a1t, a2t, v1t, v2t, g1t, g2t,
      flag, xr, xw, xk, xv, xa, xg);

  stage1_kernel<<<dim3(32, 5), 256, 0, stream>>>(xw, xa, xv, xg,
                                                 w1t, a1t, v1t, g1t, hw, ha, hv, hg);
  bigrkv_kernel<<<dim3(32, 8, 3), 256, 0, stream>>>(xr, xk, xv, cWr, cWk, cWv, (bf16*)STR);
  stage2_kernel<<<dim3(32, 8, 4), 256, 0, stream>>>(hw, ha, hv, hg,
                                                    w2t, a2t, v2t, g2t,
                                                    (bf16*)STR, (float*)STR, G,
                                                    w0, a0, v0p, vfirst, flag);
  post_kernel<<<16384, 256, 0, stream>>>((bf16*)STR, k_k, k_a, flag);
  recur_kernel<<<1024, 64, 0, stream>>>(STR, Y);
  gn_kernel<<<16384, 256, 0, stream>>>(Y, (bf16*)STR, G, gnw, gnb, r_k, flag, Z);
  outgemm_kernel<<<dim3(32, 8), 256, 0, stream>>>(Z, cWo, (float*)d_out, (bf16*)d_out, flag);
}